// Round 6
// baseline (145.605 us; speedup 1.0000x reference)
//
#include <hip/hip_runtime.h>
#include <hip/hip_bf16.h>
#include <stdint.h>
#include <stddef.h>

typedef __attribute__((ext_vector_type(8))) __bf16 bf16x8;
typedef __attribute__((ext_vector_type(4))) float f32x4;

#define DMODEL 1024
#define HEADS  16
#define BATCH  4
#define TSEQ   2048
#define MROWS  (BATCH * TSEQ)   // 8192
#define NE     (MROWS * DMODEL) // 8388608
#define NW     (DMODEL * DMODEL)

#define MiB (size_t)1048576
// layout (86.5 MiB peak). kvp aliases decB: decB dead after qkv_gemm
// (att_ln reads the ORIGINAL f32 dec for the residual).
#define QB_OFF   ((size_t)0)          // 16 MiB bf16
#define KB_OFF   (16 * MiB)           // 16 MiB bf16
#define VB_OFF   (32 * MiB)           // 16 MiB bf16
#define ENC_OFF  (48 * MiB)           // 16 MiB bf16
#define DEC_OFF  (64 * MiB)           // 16 MiB bf16
#define KVP_OFF  (64 * MiB)           // 16 MiB f32 (aliases decB)
#define WB_OFF   (80 * MiB)           // 6 MiB bf16 (Wq,Wk,Wv)
#define KVT_OFF  (86 * MiB)           // 512 KiB bf16

// ---------------------------------------------------------------------------
// one-shot f32 -> bf16 conversion: enc, dec, Wq, Wk, Wv (19.9M elems).
// grid 9728 x 256, 8 elems/thread, exact cover.
// ---------------------------------------------------------------------------
__global__ __launch_bounds__(256)
void conv_all(const float* __restrict__ enc, const float* __restrict__ dec,
              const float* __restrict__ Wq, const float* __restrict__ Wk,
              const float* __restrict__ Wv,
              __bf16* __restrict__ encB, __bf16* __restrict__ decB,
              __bf16* __restrict__ WB)
{
    const int i = (blockIdx.x * 256 + threadIdx.x) * 8;
    const float* src;
    __bf16* dst;
    int off;
    if (i < NE)            { src = enc; dst = encB; off = i; }
    else if (i < 2 * NE)   { src = dec; dst = decB; off = i - NE; }
    else {
        const int j = i - 2 * NE;           // 0..3M
        const int sel = j >> 20;            // 1M elems per W
        off = j & (NW - 1);
        src = (sel == 0) ? Wq : (sel == 1) ? Wk : Wv;
        dst = WB + (size_t)sel * NW;
    }
    f32x4 a = *(const f32x4*)(src + off);
    f32x4 b = *(const f32x4*)(src + off + 4);
    bf16x8 o;
#pragma unroll
    for (int j = 0; j < 4; ++j) { o[j] = (__bf16)a[j]; o[j + 4] = (__bf16)b[j]; }
    *(bf16x8*)(dst + off) = o;
}

// ---------------------------------------------------------------------------
// Fused QKV GEMM, m97-pure: C = A[M,K]@W[N,K]^T + bias. All-bf16 operands,
// global_load_lds width=16 for BOTH A and B (VALU = address calc only).
// 128x128 tile, BK=32, 4 waves, dbuf LDS. XCD slab decode (T1).
// This staging map is the round-3-validated gemm_bt.
// ---------------------------------------------------------------------------
__global__ __launch_bounds__(256)
void qkv_gemm(const __bf16* __restrict__ decB, const __bf16* __restrict__ encB,
              const __bf16* __restrict__ WB,
              const float* __restrict__ bq, const float* __restrict__ bk,
              const float* __restrict__ bv,
              __bf16* __restrict__ Qb, __bf16* __restrict__ Kb,
              __bf16* __restrict__ Vb)
{
    __shared__ __align__(16) __bf16 sA[2][128 * 32];
    __shared__ __align__(16) __bf16 sB[2][128 * 32];

    const int tid  = threadIdx.x;
    const int lane = tid & 63;
    const int wv   = tid >> 6;
    const int wm   = wv >> 1;
    const int wn   = wv & 1;

    const int bid  = blockIdx.x;            // 0..1535
    const int slab = bid & 7;               // XCD id (round-robin dispatch)
    const int idx  = bid >> 3;              // 0..191 within slab
    const int bm   = slab * 8 + idx / 24;   // 0..63
    const int bx   = idx % 24;
    const int sel  = bx >> 3;               // 0=Q 1=K 2=V
    const int bn   = bx & 7;

    const __bf16* A    = (sel == 0) ? decB : encB;
    const __bf16* W    = WB + (size_t)sel * NW;
    const float*  bias = (sel == 0) ? bq : (sel == 1) ? bk : bv;
    __bf16*       C    = (sel == 0) ? Qb : (sel == 1) ? Kb : Vb;

    const int l4 = lane & 15;
    const int g4 = lane >> 4;
    const int NT = DMODEL / 32;             // 32 K-steps

    // staging: tile 8192B = 8 chunks of 1024B (16 rows x 64B); wave wv does
    // chunks {wv, wv+4}; lane covers row q*16 + (lane>>2), bytes (lane&3)*16.
    const int s_row = lane >> 2;
    const int s_col = (lane & 3) * 8;

    auto stage = [&](int buf, int kt) {
        const int k0 = kt * 32 + s_col;
#pragma unroll
        for (int c2 = 0; c2 < 2; ++c2) {
            const int q = wv + c2 * 4;
            const int r = q * 16 + s_row;
            __builtin_amdgcn_global_load_lds(
                (const __attribute__((address_space(1))) void*)(A + (size_t)(bm * 128 + r) * DMODEL + k0),
                (__attribute__((address_space(3))) void*)(&sA[buf][q * 512]), 16, 0, 0);
            __builtin_amdgcn_global_load_lds(
                (const __attribute__((address_space(1))) void*)(W + (size_t)(bn * 128 + r) * DMODEL + k0),
                (__attribute__((address_space(3))) void*)(&sB[buf][q * 512]), 16, 0, 0);
        }
    };

    f32x4 acc[4][4] = {};

    stage(0, 0);
    __syncthreads();
    int buf = 0;
    for (int kt = 0; kt < NT; ++kt) {
        if (kt + 1 < NT) stage(buf ^ 1, kt + 1);

        bf16x8 af[4], bfr[4];
#pragma unroll
        for (int m = 0; m < 4; ++m)
            af[m] = *(const bf16x8*)&sA[buf][(wm * 64 + m * 16 + l4) * 32 + g4 * 8];
#pragma unroll
        for (int n = 0; n < 4; ++n)
            bfr[n] = *(const bf16x8*)&sB[buf][(wn * 64 + n * 16 + l4) * 32 + g4 * 8];

#pragma unroll
        for (int m = 0; m < 4; ++m)
#pragma unroll
            for (int n = 0; n < 4; ++n)
                acc[m][n] = __builtin_amdgcn_mfma_f32_16x16x32_bf16(af[m], bfr[n], acc[m][n], 0, 0, 0);

        __syncthreads();
        buf ^= 1;
    }

    // epilogue: C/D layout col = lane&15, row = (lane>>4)*4 + j
    const int crow0 = bm * 128 + wm * 64 + g4 * 4;
    const int ccol0 = bn * 128 + wn * 64 + l4;
#pragma unroll
    for (int n = 0; n < 4; ++n) {
        const int cc = ccol0 + n * 16;
        const float bv2 = bias[cc];
#pragma unroll
        for (int m = 0; m < 4; ++m) {
            const int rr = crow0 + m * 16;
#pragma unroll
            for (int j = 0; j < 4; ++j)
                C[(size_t)(rr + j) * DMODEL + cc] = (__bf16)(acc[m][n][j] + bv2);
        }
    }
}

// ---------------------------------------------------------------------------
// kv partials, register-tiled: block = (bh, chunk of 512 t), 4 waves.
// Lane owns an 8x8 (d,e) tile -> 64 FMA per 32 B LDS read.
// ---------------------------------------------------------------------------
__global__ __launch_bounds__(256)
void kv_mm(const __bf16* __restrict__ Kb, const __bf16* __restrict__ Vb,
           float* __restrict__ kvp)
{
    __shared__ __align__(16) float Ks[128][64];
    __shared__ __align__(16) float Vs[128][64];

    const int tid = threadIdx.x;
    const int bh  = blockIdx.x;        // 0..63
    const int ch  = blockIdx.y;        // 0..3
    const int b   = bh >> 4, h = bh & 15;
    const int w   = tid >> 6, lane = tid & 63;
    const int dg  = (lane >> 3) * 8;
    const int eg  = (lane & 7) * 8;
    const size_t base = (size_t)b * TSEQ + (size_t)ch * 512;

    f32x4 acc[8][2] = {};

    for (int ss = 0; ss < 4; ++ss) {
        __syncthreads();
#pragma unroll
        for (int i = 0; i < 4; ++i) {
            const int e = i * 2048 + tid * 8;
            const int t = e >> 6, d = e & 63;
            bf16x8 k8 = *(const bf16x8*)&Kb[(base + ss * 128 + t) * DMODEL + h * 64 + d];
            bf16x8 v8 = *(const bf16x8*)&Vb[(base + ss * 128 + t) * DMODEL + h * 64 + d];
            f32x4 kf0, kf1, vf0, vf1;
#pragma unroll
            for (int j = 0; j < 4; ++j) {
                kf0[j] = (float)k8[j]; kf1[j] = (float)k8[j + 4];
                vf0[j] = (float)v8[j]; vf1[j] = (float)v8[j + 4];
            }
            *(f32x4*)&Ks[t][d]     = kf0;
            *(f32x4*)&Ks[t][d + 4] = kf1;
            *(f32x4*)&Vs[t][d]     = vf0;
            *(f32x4*)&Vs[t][d + 4] = vf1;
        }
        __syncthreads();

#pragma unroll 4
        for (int tt = 0; tt < 32; ++tt) {
            const int t = w * 32 + tt;
            f32x4 kd0 = *(const f32x4*)&Ks[t][dg];
            f32x4 kd1 = *(const f32x4*)&Ks[t][dg + 4];
            f32x4 ve0 = *(const f32x4*)&Vs[t][eg];
            f32x4 ve1 = *(const f32x4*)&Vs[t][eg + 4];
#pragma unroll
            for (int r = 0; r < 8; ++r) {
                const float kd = (r < 4) ? kd0[r] : kd1[r - 4];
                acc[r][0] += ve0 * kd;
                acc[r][1] += ve1 * kd;
            }
        }
    }

    float* o = kvp + ((size_t)(ch * 4 + w) * 64 + bh) * 4096 + (size_t)dg * 64 + eg;
#pragma unroll
    for (int r = 0; r < 8; ++r) {
        *(f32x4*)(o + r * 64)     = acc[r][0];
        *(f32x4*)(o + r * 64 + 4) = acc[r][1];
    }
}

// ---------------------------------------------------------------------------
// reduce 16 partials; kvT[bh][e][d] = scale * sum_c kvp  (e-major for att B)
// ---------------------------------------------------------------------------
__global__ __launch_bounds__(256)
void kv_reduce(const float* __restrict__ kvp, __bf16* __restrict__ kvT)
{
    const int idx = blockIdx.x * 256 + threadIdx.x;   // 0..262143
    const int bh  = idx >> 12;
    const int rem = idx & 4095;
    const int d = rem >> 6, e = rem & 63;
    float s = 0.f;
#pragma unroll
    for (int c = 0; c < 16; ++c) s += kvp[((size_t)c * 64 + bh) * 4096 + rem];
    kvT[(size_t)bh * 4096 + e * 64 + d] = (__bf16)(s * 0.125f);   // 1/sqrt(64)
}

// ---------------------------------------------------------------------------
// att + residual + LayerNorm. 32 rows/block, 256 thr (4 waves, 4 heads each).
// Residual reads ORIGINAL f32 dec. f32 out.
// ---------------------------------------------------------------------------
__global__ __launch_bounds__(256)
void att_ln(const __bf16* __restrict__ Q, const __bf16* __restrict__ kvT,
            const float* __restrict__ dec, const float* __restrict__ gamma,
            const float* __restrict__ beta, float* __restrict__ out)
{
    __shared__ __align__(16) __bf16 att_s[32][1032];   // +8 pad

    const int tid  = threadIdx.x;
    const int lane = tid & 63;
    const int w    = tid >> 6;
    const int l4   = lane & 15, g4 = lane >> 4;
    const int t0   = blockIdx.x * 32;
    const int b    = t0 >> 11;

#pragma unroll
    for (int i = 0; i < 4; ++i) {
        const int h = w * 4 + i;
        f32x4 acc[2][4] = {};
#pragma unroll
        for (int kk = 0; kk < 2; ++kk) {
            bf16x8 a0 = *(const bf16x8*)&Q[(size_t)(t0 + l4) * DMODEL + h * 64 + kk * 32 + g4 * 8];
            bf16x8 a1 = *(const bf16x8*)&Q[(size_t)(t0 + 16 + l4) * DMODEL + h * 64 + kk * 32 + g4 * 8];
#pragma unroll
            for (int n = 0; n < 4; ++n) {
                bf16x8 bb = *(const bf16x8*)&kvT[(size_t)(b * 16 + h) * 4096 + (n * 16 + l4) * 64 + kk * 32 + g4 * 8];
                acc[0][n] = __builtin_amdgcn_mfma_f32_16x16x32_bf16(a0, bb, acc[0][n], 0, 0, 0);
                acc[1][n] = __builtin_amdgcn_mfma_f32_16x16x32_bf16(a1, bb, acc[1][n], 0, 0, 0);
            }
        }
#pragma unroll
        for (int m = 0; m < 2; ++m)
#pragma unroll
            for (int n = 0; n < 4; ++n)
#pragma unroll
                for (int j = 0; j < 4; ++j)
                    att_s[m * 16 + g4 * 4 + j][h * 64 + n * 16 + l4] = (__bf16)acc[m][n][j];
    }
    __syncthreads();

    // LN: 8 threads per row
    const int r = tid >> 3, seg = tid & 7;
    const size_t grow = (size_t)t0 + r;
    float sum = 0.f, ss2 = 0.f;
#pragma unroll
    for (int i = 0; i < 16; ++i) {
        const int c0 = seg * 8 + i * 64;
        bf16x8 av = *(const bf16x8*)&att_s[r][c0];
        f32x4 d0 = *(const f32x4*)&dec[grow * DMODEL + c0];
        f32x4 d1 = *(const f32x4*)&dec[grow * DMODEL + c0 + 4];
        bf16x8 xs;
#pragma unroll
        for (int j = 0; j < 4; ++j) {
            const float x0 = (float)av[j] + d0[j];
            const float x1 = (float)av[j + 4] + d1[j];
            sum += x0 + x1; ss2 += x0 * x0 + x1 * x1;
            xs[j] = (__bf16)x0; xs[j + 4] = (__bf16)x1;
        }
        *(bf16x8*)&att_s[r][c0] = xs;
    }
    sum += __shfl_xor(sum, 1); ss2 += __shfl_xor(ss2, 1);
    sum += __shfl_xor(sum, 2); ss2 += __shfl_xor(ss2, 2);
    sum += __shfl_xor(sum, 4); ss2 += __shfl_xor(ss2, 4);
    const float mu   = sum * (1.f / 1024.f);
    const float var  = ss2 * (1.f / 1024.f) - mu * mu;
    const float rstd = rsqrtf(var + 1e-5f);

#pragma unroll
    for (int i = 0; i < 16; ++i) {
        const int c0 = seg * 8 + i * 64;
        bf16x8 xv = *(const bf16x8*)&att_s[r][c0];
        f32x4 g0 = *(const f32x4*)&gamma[c0];
        f32x4 g1 = *(const f32x4*)&gamma[c0 + 4];
        f32x4 b0 = *(const f32x4*)&beta[c0];
        f32x4 b1 = *(const f32x4*)&beta[c0 + 4];
        f32x4 y0, y1;
#pragma unroll
        for (int j = 0; j < 4; ++j) {
            y0[j] = ((float)xv[j]     - mu) * rstd * g0[j] + b0[j];
            y1[j] = ((float)xv[j + 4] - mu) * rstd * g1[j] + b1[j];
        }
        *(f32x4*)&out[grow * DMODEL + c0]     = y0;
        *(f32x4*)&out[grow * DMODEL + c0 + 4] = y1;
    }
}

// ---------------------------------------------------------------------------
extern "C" void kernel_launch(void* const* d_in, const int* in_sizes, int n_in,
                              void* d_out, int out_size, void* d_ws, size_t ws_size,
                              hipStream_t stream)
{
    const float* enc   = (const float*)d_in[0];
    const float* dec   = (const float*)d_in[1];
    const float* Wq    = (const float*)d_in[2];
    const float* bq    = (const float*)d_in[3];
    const float* Wk    = (const float*)d_in[4];
    const float* bk    = (const float*)d_in[5];
    const float* Wv    = (const float*)d_in[6];
    const float* bv    = (const float*)d_in[7];
    const float* gamma = (const float*)d_in[8];
    const float* beta  = (const float*)d_in[9];

    char* ws = (char*)d_ws;
    __bf16* Qb   = (__bf16*)(ws + QB_OFF);
    __bf16* Kb   = (__bf16*)(ws + KB_OFF);
    __bf16* Vb   = (__bf16*)(ws + VB_OFF);
    __bf16* encB = (__bf16*)(ws + ENC_OFF);
    __bf16* decB = (__bf16*)(ws + DEC_OFF);
    float*  kvp  = (float*) (ws + KVP_OFF);   // aliases decB (dead after gemm)
    __bf16* WB   = (__bf16*)(ws + WB_OFF);
    __bf16* kvT  = (__bf16*)(ws + KVT_OFF);

    conv_all<<<9728, 256, 0, stream>>>(enc, dec, Wq, Wk, Wv, encB, decB, WB);
    qkv_gemm<<<1536, 256, 0, stream>>>(decB, encB, WB, bq, bk, bv, Qb, Kb, Vb);
    kv_mm<<<dim3(64, 4), 256, 0, stream>>>(Kb, Vb, kvp);
    kv_reduce<<<1024, 256, 0, stream>>>(kvp, kvT);
    att_ln<<<256, 256, 0, stream>>>(Qb, kvT, dec, gamma, beta, (float*)d_out);
}